// Round 8
// baseline (223.713 us; speedup 1.0000x reference)
//
#include <hip/hip_runtime.h>
#include <stdint.h>

// SelfCrossAttn bf16-MFMA pipeline v8. b=4, c=512, N=4096, HEADS=4.
// All GEMMs NT: C[m][n] = sum_k A[m][k]*B[n][k], operands k-contiguous.
// kk' = s*128+t permutation (s=n>>10, t=c&127) applied uniformly to S cols
// and vT' rows; sum over kk is order-agnostic.
//  prep      : W* fp32->bf16 (Wb) ; x[b][c][n] -> xT[b][n][c] bf16
//  gemm_qkv  : q/k[b][o][n] bf16 natural; V direct-stored vT'[slab][e][kk']
//  gemm_qk   : split-K x2: S_half[qq][kk'] partials (fp32, scaled)
//  gemm_pv_sm: FUSED softmax+PV. Max-free softmax (logits are O(1); exp in
//              fp32, clamped): per K-iter load S0+S1 tile, exp -> bf16 A-tile
//              in LDS, accumulate per-row l; O = (exp(S).V)/l in epilogue.
//              P is never materialized. Scatters into yT[n][c].
//  gemm_proj : out = Wproj @ y + bias + x (NT vs yT), fp32

typedef __attribute__((ext_vector_type(8))) short short8;
typedef __attribute__((ext_vector_type(4))) float f32x4;

typedef const __attribute__((address_space(1))) unsigned int* gas_ptr;
typedef __attribute__((address_space(3))) unsigned int* las_ptr;

#define ATTN_SCALE 0.08838834764831845f   // 128^-0.5

__device__ __forceinline__ unsigned short f2bf(float f) {
    union { float f; unsigned int u; } c; c.f = f;
    unsigned int u = c.u;
    u += 0x7fffu + ((u >> 16) & 1u);      // RNE
    return (unsigned short)(u >> 16);
}

__device__ __forceinline__ void gl_lds16(const void* g, void* l) {
    __builtin_amdgcn_global_load_lds((gas_ptr)(uintptr_t)g, (las_ptr)(uintptr_t)l,
                                     16, 0, 0);
}

// ---- shared MFMA core: 128x128 C-tile, 4 waves, BK=32, 16x16x32 bf16 ----
// PERMB: B rows are logical kk' -> physical slab row 4*(kk'&127) + (kk'>>7).
template<int LDA, int LDB, int KDIM, bool PERMB = false>
__device__ __forceinline__ void mfma_core(
    const unsigned short* __restrict__ A,
    const unsigned short* __restrict__ B,
    int m0, int n0,
    unsigned short* __restrict__ sA, unsigned short* __restrict__ sB,
    f32x4 acc[4][4])
{
    const int tid  = threadIdx.x;
    const int lane = tid & 63, wave = tid >> 6;
    const int lr = lane >> 2, lc = lane & 3;       // staging: 16 rows x 4 chunks
    const int wm = (wave & 1) * 64, wn = (wave >> 1) * 64;
    const int col = lane & 15, quad = lane >> 4;

    const unsigned short* ga = A + (size_t)(m0 + 32 * wave + lr) * LDA + lc * 8;
    int rb0 = n0 + 32 * wave + lr;
    int rb1 = rb0 + 16;
    if (PERMB) {
        rb0 = 4 * (rb0 & 127) + (rb0 >> 7);
        rb1 = 4 * (rb1 & 127) + (rb1 >> 7);
    }
    const unsigned short* gb0 = B + (size_t)rb0 * LDB + lc * 8;
    const unsigned short* gb1 = B + (size_t)rb1 * LDB + lc * 8;

    unsigned short* la0 = sA + (32 * wave) * 32;
    unsigned short* la1 = sA + (32 * wave + 16) * 32;
    unsigned short* lb0 = sB + (32 * wave) * 32;
    unsigned short* lb1 = sB + (32 * wave + 16) * 32;

    for (int k0 = 0; k0 < KDIM; k0 += 32) {
        gl_lds16(ga + k0,            la0);
        gl_lds16(ga + k0 + 16 * LDA, la1);
        gl_lds16(gb0 + k0,           lb0);
        gl_lds16(gb1 + k0,           lb1);
        __syncthreads();
        short8 af[4], bf[4];
        #pragma unroll
        for (int i = 0; i < 4; ++i)
            af[i] = *(const short8*)&sA[(wm + i * 16 + col) * 32 + quad * 8];
        #pragma unroll
        for (int j = 0; j < 4; ++j)
            bf[j] = *(const short8*)&sB[(wn + j * 16 + col) * 32 + quad * 8];
        #pragma unroll
        for (int i = 0; i < 4; ++i)
            #pragma unroll
            for (int j = 0; j < 4; ++j)
                acc[i][j] = __builtin_amdgcn_mfma_f32_16x16x32_bf16(
                    af[i], bf[j], acc[i][j], 0, 0, 0);
        __syncthreads();
    }
}

// ---- prep: z<4 -> transpose x[b][c][n]->xT[b][n][c] bf16 ; z==4 -> W conv ----
__global__ __launch_bounds__(256)
void prep(const float* __restrict__ x,
          const float* __restrict__ Wq, const float* __restrict__ Wk,
          const float* __restrict__ Wv, const float* __restrict__ Wp,
          unsigned short* __restrict__ xT, unsigned short* __restrict__ Wb)
{
    if (blockIdx.z == 4) {
        const int idx = (blockIdx.y * 64 + blockIdx.x) * 256 + threadIdx.x; // 262144
        const int mat = idx >> 16;
        const int off = (idx & 65535) << 2;
        const float* src = (mat == 0 ? Wq : mat == 1 ? Wk : mat == 2 ? Wv : Wp) + off;
        const float4 f = *(const float4*)src;
        uint2 o;
        o.x = f2bf(f.x) | ((unsigned)f2bf(f.y) << 16);
        o.y = f2bf(f.z) | ((unsigned)f2bf(f.w) << 16);
        *(uint2*)&Wb[mat * 262144 + off] = o;
        return;
    }
    const int b = blockIdx.z;
    const int l = threadIdx.x & 63, w = threadIdx.x >> 6;
    const int n  = blockIdx.x * 64 + l;
    const int c0 = blockIdx.y * 32 + w * 8;
    const float* xp = x + (size_t)b * 2097152 + (size_t)c0 * 4096 + n;
    unsigned int p[4];
    #pragma unroll
    for (int j = 0; j < 4; ++j) {
        const unsigned short a  = f2bf(xp[(2 * j)     * 4096]);
        const unsigned short bb = f2bf(xp[(2 * j + 1) * 4096]);
        p[j] = a | ((unsigned)bb << 16);
    }
    uint4 v; v.x = p[0]; v.y = p[1]; v.z = p[2]; v.w = p[3];
    *(uint4*)&xT[(size_t)b * 2097152 + (size_t)n * 512 + c0] = v;
}

// ---- K1: q/k = W @ x natural [o][n]; V direct-stored as vT'[slab][e][kk'] ----
__global__ __launch_bounds__(256)
void gemm_qkv(const unsigned short* __restrict__ Wb,
              const unsigned short* __restrict__ xT,
              unsigned short* __restrict__ qb, unsigned short* __restrict__ kb,
              unsigned short* __restrict__ vT)
{
    __shared__ unsigned short sA[128 * 32], sB[128 * 32];

    const int z = blockIdx.z, wsel = z >> 2, b = z & 3;
    const unsigned short* A = Wb + wsel * 262144;
    const unsigned short* B = xT + (size_t)b * 2097152;
    const int m0 = blockIdx.y * 128, n0 = blockIdx.x * 128;

    f32x4 z4 = {0.f, 0.f, 0.f, 0.f};
    f32x4 acc[4][4];
    #pragma unroll
    for (int i = 0; i < 4; ++i)
        #pragma unroll
        for (int j = 0; j < 4; ++j) acc[i][j] = z4;

    mfma_core<512, 512, 512>(A, B, m0, n0, sA, sB, acc);

    const int lane = threadIdx.x & 63, wave = threadIdx.x >> 6;
    const int wm = (wave & 1) * 64, wn = (wave >> 1) * 64;
    const int col = lane & 15, quad = lane >> 4;

    if (wsel < 2) {
        unsigned short* C = (wsel == 0 ? qb : kb) + (size_t)b * 2097152;
        #pragma unroll
        for (int i = 0; i < 4; ++i)
            #pragma unroll
            for (int r = 0; r < 4; ++r) {
                const int row = m0 + wm + i * 16 + quad * 4 + r;
                #pragma unroll
                for (int j = 0; j < 4; ++j)
                    C[(size_t)row * 4096 + n0 + wn + j * 16 + col] = f2bf(acc[i][j][r]);
            }
    } else {
        // V tile: m = channel c -> head h = m0>>7; n -> s = n0>>10, e local.
        // Lane tile (i,j): 4 acc rows = 4 consecutive kk'. Direct uint2 store.
        const int h = m0 >> 7, s = n0 >> 10, e0 = n0 & 1023;
        unsigned short* dst = vT + (size_t)(b * 4 + h) * 524288 + s * 128;
        #pragma unroll
        for (int i = 0; i < 4; ++i) {
            const int kb2 = wm + i * 16 + quad * 4;
            #pragma unroll
            for (int j = 0; j < 4; ++j) {
                const int e = e0 + wn + j * 16 + col;
                uint2 o;
                o.x = f2bf(acc[i][j][0]) | ((unsigned)f2bf(acc[i][j][1]) << 16);
                o.y = f2bf(acc[i][j][2]) | ((unsigned)f2bf(acc[i][j][3]) << 16);
                *(uint2*)&dst[(size_t)e * 512 + kb2] = o;
            }
        }
    }
}

// ---- K2: split-K x2: S_half[qq][kk'] = scale * Q K^T partial ----
__global__ __launch_bounds__(256)
void gemm_qk(const unsigned short* __restrict__ qb,
             const unsigned short* __restrict__ kb,
             float* __restrict__ S)
{
    __shared__ unsigned short sA[128 * 32], sB[128 * 32];
    const int z = blockIdx.z;                 // slab*2 + half
    const int slab = z >> 1, half = z & 1;
    const unsigned short* A = qb + (size_t)slab * 524288 + half * 512;
    const unsigned short* B = kb + (size_t)slab * 524288 + half * 512;
    float* Sp = S + (size_t)half * 4194304 + (size_t)slab * 262144;
    const int m0 = blockIdx.y * 128, n0 = blockIdx.x * 128;

    f32x4 z4 = {0.f, 0.f, 0.f, 0.f};
    f32x4 acc[4][4];
    #pragma unroll
    for (int i = 0; i < 4; ++i)
        #pragma unroll
        for (int j = 0; j < 4; ++j) acc[i][j] = z4;

    mfma_core<1024, 1024, 512, true>(A, B, m0, n0, sA, sB, acc);

    const int lane = threadIdx.x & 63, wave = threadIdx.x >> 6;
    const int wm = (wave & 1) * 64, wn = (wave >> 1) * 64;
    const int col = lane & 15, quad = lane >> 4;
    #pragma unroll
    for (int i = 0; i < 4; ++i)
        #pragma unroll
        for (int r = 0; r < 4; ++r) {
            const int row = m0 + wm + i * 16 + quad * 4 + r;
            #pragma unroll
            for (int j = 0; j < 4; ++j)
                Sp[(size_t)row * 512 + n0 + wn + j * 16 + col] =
                    acc[i][j][r] * ATTN_SCALE;
        }
}

// ---- K3+K4 FUSED: O = softmax_row(S) V' per slab; scatter into yT[n][c] ----
// Max-free softmax: P = exp(S) (fp32 exp, clamped at 80), O = (P.V)/l.
// Per K-iter: thread (row=tid>>1, half=tid&1) loads 16 fp32 of S0+S1, exps,
// accumulates per-row l partial, writes bf16 A-tile to LDS; B staged via
// global_load_lds as usual.
__global__ __launch_bounds__(256)
void gemm_pv_sm(const float* __restrict__ S,
                const unsigned short* __restrict__ vT,
                unsigned short* __restrict__ yT)
{
    __shared__ unsigned short sT[128 * 136];   // 34816 B; K-loop uses front 16 KB
    __shared__ float sLh[256];                 // per-(row,half) l partials
    unsigned short* sA = sT;                   // [128][32] bf16 (exp(S) tile)
    unsigned short* sB = sT + 4096;            // [128][32] bf16 (vT' tile)

    const int z = blockIdx.z, b = z >> 2, hh = z & 3;
    const float* S0 = S + (size_t)z * 262144;            // [512][512] half 0
    const float* S1 = S0 + 4194304;                      // half 1
    const unsigned short* B = vT + (size_t)z * 524288;   // [1024][512] kk'-rows
    unsigned short* yTb = yT + (size_t)b * 2097152;
    const int m0 = blockIdx.y * 128;   // qq
    const int n0 = blockIdx.x * 128;   // e

    const int tid = threadIdx.x;
    const int lane = tid & 63, wave = tid >> 6;
    const int lr = lane >> 2, lc = lane & 3;
    const int wm = (wave & 1) * 64, wn = (wave >> 1) * 64;
    const int col = lane & 15, quad = lane >> 4;

    // B staging addresses (mfma_core pattern, B only)
    const unsigned short* gb0 = B + (size_t)(n0 + 32 * wave + lr) * 512 + lc * 8;
    const unsigned short* gb1 = gb0 + (size_t)16 * 512;
    unsigned short* lb0 = sB + (32 * wave) * 32;
    unsigned short* lb1 = sB + (32 * wave + 16) * 32;

    // S conversion addresses: thread -> (row, 16-col half)
    const int srow = tid >> 1;
    const int shalf = (tid & 1) << 4;
    const float* s0p = S0 + (size_t)(m0 + srow) * 512 + shalf;
    const float* s1p = S1 + (size_t)(m0 + srow) * 512 + shalf;
    unsigned short* sArow = sA + srow * 32 + shalf;

    f32x4 z4 = {0.f, 0.f, 0.f, 0.f};
    f32x4 acc[4][4];
    #pragma unroll
    for (int i = 0; i < 4; ++i)
        #pragma unroll
        for (int j = 0; j < 4; ++j) acc[i][j] = z4;

    float lpart = 0.f;

    for (int k0 = 0; k0 < 512; k0 += 32) {
        gl_lds16(gb0 + k0, lb0);
        gl_lds16(gb1 + k0, lb1);
        // exp-convert 16 S values -> bf16 A-tile
        float v[16];
        #pragma unroll
        for (int t = 0; t < 4; ++t) {
            const float4 a0 = *(const float4*)&s0p[k0 + t * 4];
            const float4 a1 = *(const float4*)&s1p[k0 + t * 4];
            v[t * 4 + 0] = a0.x + a1.x; v[t * 4 + 1] = a0.y + a1.y;
            v[t * 4 + 2] = a0.z + a1.z; v[t * 4 + 3] = a0.w + a1.w;
        }
        unsigned int pk[8];
        #pragma unroll
        for (int t = 0; t < 8; ++t) {
            const float e0 = __expf(fminf(v[2 * t],     80.f));
            const float e1 = __expf(fminf(v[2 * t + 1], 80.f));
            lpart += e0 + e1;
            pk[t] = f2bf(e0) | ((unsigned)f2bf(e1) << 16);
        }
        uint4 lo; lo.x = pk[0]; lo.y = pk[1]; lo.z = pk[2]; lo.w = pk[3];
        uint4 hi; hi.x = pk[4]; hi.y = pk[5]; hi.z = pk[6]; hi.w = pk[7];
        *(uint4*)&sArow[0] = lo;
        *(uint4*)&sArow[8] = hi;
        __syncthreads();
        short8 af[4], bf[4];
        #pragma unroll
        for (int i = 0; i < 4; ++i)
            af[i] = *(const short8*)&sA[(wm + i * 16 + col) * 32 + quad * 8];
        #pragma unroll
        for (int j = 0; j < 4; ++j)
            bf[j] = *(const short8*)&sB[(wn + j * 16 + col) * 32 + quad * 8];
        #pragma unroll
        for (int i = 0; i < 4; ++i)
            #pragma unroll
            for (int j = 0; j < 4; ++j)
                acc[i][j] = __builtin_amdgcn_mfma_f32_16x16x32_bf16(
                    af[i], bf[j], acc[i][j], 0, 0, 0);
        __syncthreads();
    }

    sLh[tid] = lpart;           // tid == srow*2 + (tid&1)
    __syncthreads();

    // per-row inverse sums for this lane's 16 acc rows
    float inv[4][4];
    #pragma unroll
    for (int i = 0; i < 4; ++i)
        #pragma unroll
        for (int r = 0; r < 4; ++r) {
            const int row = wm + i * 16 + quad * 4 + r;
            inv[i][r] = 1.f / (sLh[2 * row] + sLh[2 * row + 1]);
        }

    // D tile -> LDS [qq_local][e_local], pad 136 (overwrites sA/sB)
    #pragma unroll
    for (int i = 0; i < 4; ++i)
        #pragma unroll
        for (int r = 0; r < 4; ++r) {
            const int rr = wm + i * 16 + quad * 4 + r;
            #pragma unroll
            for (int j = 0; j < 4; ++j)
                sT[rr * 136 + wn + j * 16 + col] = f2bf(acc[i][j][r] * inv[i][r]);
        }
    __syncthreads();

    // pack 16-elem c-runs: yT[(s<<9)+qq][hh*128 + (n0>>3) + tt], tt=0..15
    #pragma unroll
    for (int k = 0; k < 4; ++k) {
        const int rid = k * 256 + tid;       // 0..1023
        const int qq_l = rid >> 3, s = rid & 7;
        const unsigned short* Trow = sT + qq_l * 136;
        unsigned int p[8];
        #pragma unroll
        for (int t = 0; t < 8; ++t) {
            const unsigned int a  = Trow[s + 8 * (2 * t)];
            const unsigned int bb = Trow[s + 8 * (2 * t + 1)];
            p[t] = a | (bb << 16);
        }
        const size_t base = (size_t)((s << 9) + m0 + qq_l) * 512 + hh * 128 + (n0 >> 3);
        uint4 lo; lo.x = p[0]; lo.y = p[1]; lo.z = p[2]; lo.w = p[3];
        uint4 hi; hi.x = p[4]; hi.y = p[5]; hi.z = p[6]; hi.w = p[7];
        *(uint4*)&yTb[base]     = lo;
        *(uint4*)&yTb[base + 8] = hi;
    }
}

// ---- K5: out = Wproj @ y + bias + x (NT vs yT), fp32 out ----
__global__ __launch_bounds__(256)
void gemm_proj(const unsigned short* __restrict__ Wpb,
               const unsigned short* __restrict__ yT,
               const float* __restrict__ bias, const float* __restrict__ x,
               float* __restrict__ out)
{
    __shared__ unsigned short sA[128 * 32], sB[128 * 32];
    const int b = blockIdx.z;
    const unsigned short* B = yT + (size_t)b * 2097152;  // [4096][512]
    const int m0 = blockIdx.y * 128, n0 = blockIdx.x * 128;

    f32x4 z4 = {0.f, 0.f, 0.f, 0.f};
    f32x4 acc[4][4];
    #pragma unroll
    for (int i = 0; i < 4; ++i)
        #pragma unroll
        for (int j = 0; j < 4; ++j) acc[i][j] = z4;

    mfma_core<512, 512, 512>(Wpb, B, m0, n0, sA, sB, acc);

    const int lane = threadIdx.x & 63, wave = threadIdx.x >> 6;
    const int wm = (wave & 1) * 64, wn = (wave >> 1) * 64;
    const int col = lane & 15, quad = lane >> 4;
    const size_t boff = (size_t)b * 2097152;
    #pragma unroll
    for (int i = 0; i < 4; ++i)
        #pragma unroll
        for (int r = 0; r < 4; ++r) {
            const int row = m0 + wm + i * 16 + quad * 4 + r;
            const float bi = bias[row];
            #pragma unroll
            for (int j = 0; j < 4; ++j) {
                const size_t idx = boff + (size_t)row * 4096 + n0 + wn + j * 16 + col;
                out[idx] = acc[i][j][r] + bi + x[idx];
            }
        }
}

extern "C" void kernel_launch(void* const* d_in, const int* in_sizes, int n_in,
                              void* d_out, int out_size, void* d_ws, size_t ws_size,
                              hipStream_t stream) {
    const float* x     = (const float*)d_in[0];
    const float* Wq    = (const float*)d_in[1];
    const float* Wk    = (const float*)d_in[2];
    const float* Wv    = (const float*)d_in[3];
    const float* Wproj = (const float*)d_in[4];
    const float* bproj = (const float*)d_in[5];
    float* out = (float*)d_out;

    char* w = (char*)d_ws;
    unsigned short* xT = (unsigned short*)(w + 0);          // 16 MB [b][n][c]
    unsigned short* qb = (unsigned short*)(w + 16777216);   // 16 MB [b][o][n]
    unsigned short* kb = (unsigned short*)(w + 33554432);   // 16 MB
    unsigned short* vT = (unsigned short*)(w + 50331648);   // 16 MB [slab][e][kk']
    float*          S  = (float*)        (w + 67108864);    // 32 MB fp32 (2 halves)
    unsigned short* Wb = (unsigned short*)(w + 100663296);  //  2 MB
    unsigned short* yT = xT;   // xT dead after gemm_qkv

    prep       <<<dim3(64, 16, 5),  256, 0, stream>>>(x, Wq, Wk, Wv, Wproj, xT, Wb);
    gemm_qkv   <<<dim3(32, 4, 12),  256, 0, stream>>>(Wb, xT, qb, kb, vT);
    gemm_qk    <<<dim3(4, 4, 32),   256, 0, stream>>>(qb, kb, S);
    gemm_pv_sm <<<dim3(8, 4, 16),   256, 0, stream>>>(S, vT, yT);
    gemm_proj  <<<dim3(32, 4, 4),   256, 0, stream>>>(Wb + 3 * 262144, yT, bproj, x, out);
}